// Round 5
// baseline (1103.225 us; speedup 1.0000x reference)
//
#include <hip/hip_runtime.h>
#include <hip/hip_bf16.h>
#include <stdint.h>

#define NN 10000     // nodes
#define NE 320000    // edges
#define KK 256       // IN
#define DO 128       // OUT

typedef __attribute__((ext_vector_type(8))) short bf16x8;
typedef __attribute__((ext_vector_type(4))) short bf16x4;
typedef __attribute__((ext_vector_type(4))) float f32x4;
typedef __attribute__((ext_vector_type(2))) float f32x2;

static __device__ __forceinline__ unsigned short f2bf(float x) {
  union { float f; uint32_t u; } v; v.f = x;
  return (unsigned short)((v.u + 0x7FFFu + ((v.u >> 16) & 1u)) >> 16);  // RNE
}
static __device__ __forceinline__ short f2bfs(float x) {   // fast HW cvt
  return (short)__bfloat16_as_ushort(__float2bfloat16(x));
}
static __device__ __forceinline__ float bf2f(uint32_t bits16) {
  union { uint32_t u; float f; } v; v.u = bits16 << 16;
  return v.f;
}

// ---------------------------------------------------------------------------
// prep: bf16 weight images in the LDS layout the GEMMs read.
// Group (chunk c, col, slot s): 8 bf16 = Wt[col][k0..k0+8),
//   k0 = c*32 + ((s ^ ((col>>1)&3)) << 3)
// Edge image: 256 cols = [W_prj_edge | W_edge]. Node: 5 mats x 128 cols.
// ---------------------------------------------------------------------------
__global__ void nig_prep(const float* __restrict__ Wpe, const float* __restrict__ We,
                         const float* __restrict__ W0, const float* __restrict__ W1,
                         const float* __restrict__ W2, const float* __restrict__ W3,
                         const float* __restrict__ W4,
                         const float* __restrict__ bps, const float* __restrict__ bpd,
                         const float* __restrict__ bpe,
                         short* __restrict__ img_edge, short* __restrict__ img_node,
                         float* __restrict__ bsum) {
  int gid = blockIdx.x * 256 + threadIdx.x;
  if (gid < DO) bsum[gid] = bps[gid] + bpd[gid] + bpe[gid];
  const int EG = 8 * 256 * 4;   // 8192 edge groups
  const int NG = 8 * 128 * 4;   // 4096 groups per node mat
  if (gid >= EG + 5 * NG) return;
  const float* W; int col, c, s; short* dstp;
  if (gid < EG) {
    c = gid >> 10; int rem = gid & 1023; col = rem >> 2; s = rem & 3;
    W = (col < DO) ? (Wpe + col) : (We + (col - DO));
    dstp = img_edge + (size_t)gid * 8;
  } else {
    int g = gid - EG; int m = g >> 12; int rem = g & 4095;
    c = rem >> 9; int r2 = rem & 511; col = r2 >> 2; s = r2 & 3;
    const float* Wm = (m == 0) ? W0 : (m == 1) ? W1 : (m == 2) ? W2 : (m == 3) ? W3 : W4;
    W = Wm + col;
    dstp = img_node + (size_t)g * 8;
  }
  int k0 = c * 32 + ((s ^ ((col >> 1) & 3)) << 3);
  short tmp[8];
#pragma unroll
  for (int i = 0; i < 8; ++i) tmp[i] = (short)f2bf(W[(size_t)(k0 + i) * DO]);
  *(bf16x8*)dstp = *(const bf16x8*)tmp;
}

// ---------------------------------------------------------------------------
// Node GEMM: 64-row tiles, waves split the 128 output cols in halves.
// grid (157, 5): y selects matrix; 0-2 bf16 out (hwS,hwD,hsB), 3-4 f32.
// ---------------------------------------------------------------------------
__global__ __launch_bounds__(256, 2) void nig_gemm_node(
    const float* __restrict__ A, int M,
    const short* __restrict__ img_all,
    short* __restrict__ ob0, short* __restrict__ ob1, short* __restrict__ ob2,
    float* __restrict__ of3, float* __restrict__ of4) {
  constexpr int CHUNK = 8192;   // 128 cols * 64 B
  __shared__ char lds[2 * CHUNK];

  const int tid = threadIdx.x;
  const int wv = tid >> 6;
  const int ln = tid & 63;
  const int l15 = ln & 15;
  const int l4 = ln >> 4;
  const int by = blockIdx.y;
  const short* __restrict__ img = img_all + (size_t)by * 32768;
  const int row_base = blockIdx.x * 64 + (wv & 1) * 32;
  const int fbase = (wv >> 1) * 4;   // column-half select
  const int rd_off = l15 * 64 + ((l4 ^ ((l15 >> 1) & 3)) << 4);

  f32x4 acc[2][4];
#pragma unroll
  for (int e = 0; e < 2; ++e)
#pragma unroll
    for (int f = 0; f < 4; ++f) acc[e][f] = (f32x4)0.f;

#pragma unroll
  for (int r = 0; r < 2; ++r) {
    int off = r * 4096 + tid * 16;
    *(bf16x8*)(lds + off) = *(const bf16x8*)((const char*)img + off);
  }
  __syncthreads();

  for (int c = 0; c < 8; ++c) {
    const int cur = c & 1;
    bf16x8 nx[2];
    if (c < 7) {
#pragma unroll
      for (int r = 0; r < 2; ++r) {
        int off = r * 4096 + tid * 16;
        nx[r] = *(const bf16x8*)((const char*)img + (size_t)(c + 1) * CHUNK + off);
      }
    }
    bf16x8 af[2];
#pragma unroll
    for (int e = 0; e < 2; ++e) {
      int row = row_base + e * 16 + l15;
      f32x4 lo = (f32x4)0.f, hi = (f32x4)0.f;
      if (row < M) {
        const float* ap = A + (size_t)row * KK + c * 32 + l4 * 8;
        lo = *(const f32x4*)ap;
        hi = *(const f32x4*)(ap + 4);
      }
      bf16x8 t;
#pragma unroll
      for (int j = 0; j < 4; ++j) { t[j] = f2bfs(lo[j]); t[4 + j] = f2bfs(hi[j]); }
      af[e] = t;
    }
    const char* buf = lds + cur * CHUNK;
#pragma unroll
    for (int f = 0; f < 4; ++f) {
      bf16x8 wf = *(const bf16x8*)(buf + (fbase + f) * 1024 + rd_off);
      acc[0][f] = __builtin_amdgcn_mfma_f32_16x16x32_bf16(wf, af[0], acc[0][f], 0, 0, 0);
      acc[1][f] = __builtin_amdgcn_mfma_f32_16x16x32_bf16(wf, af[1], acc[1][f], 0, 0, 0);
    }
    if (c < 7) {
#pragma unroll
      for (int r = 0; r < 2; ++r) {
        int off = r * 4096 + tid * 16;
        *(bf16x8*)(lds + (cur ^ 1) * CHUNK + off) = nx[r];
      }
    }
    __syncthreads();
  }

  short* ob = (by == 0) ? ob0 : (by == 1) ? ob1 : ob2;
  float* of = (by == 3) ? of3 : of4;
  const bool isf = (by >= 3);
#pragma unroll
  for (int e = 0; e < 2; ++e) {
    int row = row_base + e * 16 + l15;
    if (row >= M) continue;
#pragma unroll
    for (int f = 0; f < 4; ++f) {
      int c0 = (fbase + f) * 16 + l4 * 4;
      f32x4 v = acc[e][f];
      if (!isf) {
        bf16x4 p;
#pragma unroll
        for (int j = 0; j < 4; ++j) p[j] = f2bfs(v[j]);
        *(bf16x4*)(ob + (size_t)row * 128 + c0) = p;
      } else {
        *(f32x4*)(of + (size_t)row * 128 + c0) = v;
      }
    }
  }
}

// ---------------------------------------------------------------------------
// Edge GEMM v2: persistent. Whole 128 KB [W_prj_edge|W_edge] image in LDS
// (staged once, ONE barrier total). 250 blocks x 512 thr; each block does 5
// tiles of 256 rows. A-loads software-pipelined 4 chunks deep (slot = chunk%4,
// fully unrolled -> registers), crossing tile boundaries. Fused epilogue:
// logit (PReLU + W_att dot) and dst-sorted stores via rank[].
// ---------------------------------------------------------------------------
__global__ __launch_bounds__(512, 2) void nig_gemm_edge(
    const float* __restrict__ A,
    const short* __restrict__ img,
    const short* __restrict__ hwS, const short* __restrict__ hwD,
    const float* __restrict__ bsum, const float* __restrict__ Watt,
    const float* __restrict__ batt_p, const float* __restrict__ alpha_p,
    const float* __restrict__ b_edge,
    const int* __restrict__ src, const int* __restrict__ dst,
    const int* __restrict__ rank,
    float* __restrict__ logits_s, int* __restrict__ src_s,
    short* __restrict__ ewe_s) {
  __shared__ char lds[131072];   // full image: 8 chunks x 16 KB

  const int tid = threadIdx.x;
  const int wv = tid >> 6;
  const int ln = tid & 63;
  const int l15 = ln & 15;
  const int l4 = ln >> 4;
  const int bid = blockIdx.x;    // 0..249
  const int rd_off = l15 * 64 + ((l4 ^ ((l15 >> 1) & 3)) << 4);

  // stage whole image once
#pragma unroll
  for (int r = 0; r < 16; ++r) {
    int off = r * 8192 + tid * 16;
    *(bf16x8*)(lds + off) = *(const bf16x8*)((const char*)img + off);
  }
  __syncthreads();

  const float alpha = alpha_p[0];
  const float batt = batt_p[0];

  f32x4 acc0[16], acc1[16];
#pragma unroll
  for (int f = 0; f < 16; ++f) { acc0[f] = (f32x4)0.f; acc1[f] = (f32x4)0.f; }

  f32x4 ra[4], rb[4], rc[4], rd[4];   // pipeline slots (static idx after unroll)
  auto issue = [&](int slot, int t, int ch) {
    const float* p0 = A + (((size_t)((t << 8) + (wv << 5) + l15)) << 8) + (ch << 5) + (l4 << 3);
    ra[slot] = *(const f32x4*)p0;
    rb[slot] = *(const f32x4*)(p0 + 4);
    const float* p1 = p0 + (16 << 8);
    rc[slot] = *(const f32x4*)p1;
    rd[slot] = *(const f32x4*)(p1 + 4);
  };

  // prologue: chunks 0..3 of first tile
  issue(0, bid, 0); issue(1, bid, 1); issue(2, bid, 2); issue(3, bid, 3);

  for (int t = bid; t < 1250; t += 250) {
    const bool hn = (t + 250 < 1250);
    const int r0 = (t << 8) + (wv << 5) + l15;
    const int r1 = r0 + 16;
    const int s0 = src[r0], d0 = dst[r0], k0 = rank[r0];
    const int s1 = src[r1], d1 = dst[r1], k1 = rank[r1];

#pragma unroll
    for (int c = 0; c < 8; ++c) {
      const int sl = c & 3;
      // consume slot -> bf16 fragments
      bf16x8 af0, af1;
#pragma unroll
      for (int j = 0; j < 4; ++j) {
        af0[j] = f2bfs(ra[sl][j]); af0[4 + j] = f2bfs(rb[sl][j]);
        af1[j] = f2bfs(rc[sl][j]); af1[4 + j] = f2bfs(rd[sl][j]);
      }
      // re-issue this slot 4 chunks ahead (crossing into next tile)
      if (c < 4) issue(sl, t, c + 4);
      else if (hn) issue(sl, t + 250, c - 4);
      // MFMA against LDS-resident weights
      const char* buf = lds + (c << 14);
#pragma unroll
      for (int f = 0; f < 16; ++f) {
        bf16x8 wf = *(const bf16x8*)(buf + f * 1024 + rd_off);
        acc0[f] = __builtin_amdgcn_mfma_f32_16x16x32_bf16(wf, af0, acc0[f], 0, 0, 0);
        acc1[f] = __builtin_amdgcn_mfma_f32_16x16x32_bf16(wf, af1, acc1[f], 0, 0, 0);
      }
    }

    // fused epilogue (per row-fragment)
#pragma unroll
    for (int e = 0; e < 2; ++e) {
      const int s = e ? s1 : s0;
      const int d = e ? d1 : d0;
      const int rk = e ? k1 : k0;
      f32x4* accp = e ? acc1 : acc0;
      float at = 0.f;
#pragma unroll
      for (int f = 0; f < 8; ++f) {
        const int c0 = f * 16 + l4 * 4;
        uint2 hsp = *(const uint2*)(hwS + (size_t)s * 128 + c0);
        uint2 hdp = *(const uint2*)(hwD + (size_t)d * 128 + c0);
        f32x4 bs = *(const f32x4*)(bsum + c0);
        f32x4 wa = *(const f32x4*)(Watt + c0);
        f32x4 v = accp[f];
        float w0 = v[0] + bf2f(hsp.x & 0xffffu) + bf2f(hdp.x & 0xffffu) + bs[0];
        float w1 = v[1] + bf2f(hsp.x >> 16)     + bf2f(hdp.x >> 16)     + bs[1];
        float w2 = v[2] + bf2f(hsp.y & 0xffffu) + bf2f(hdp.y & 0xffffu) + bs[2];
        float w3 = v[3] + bf2f(hsp.y >> 16)     + bf2f(hdp.y >> 16)     + bs[3];
        w0 = (w0 >= 0.f) ? w0 : alpha * w0;
        w1 = (w1 >= 0.f) ? w1 : alpha * w1;
        w2 = (w2 >= 0.f) ? w2 : alpha * w2;
        w3 = (w3 >= 0.f) ? w3 : alpha * w3;
        at += w0 * wa[0] + w1 * wa[1] + w2 * wa[2] + w3 * wa[3];
      }
      at += __shfl_xor(at, 16, 64);
      at += __shfl_xor(at, 32, 64);
      if (l4 == 0) { logits_s[rk] = at + batt; src_s[rk] = s; }
#pragma unroll
      for (int f = 0; f < 8; ++f) {
        const int c0 = f * 16 + l4 * 4;
        f32x4 v = accp[8 + f];
        f32x4 be = *(const f32x4*)(b_edge + c0);
        bf16x4 p;
#pragma unroll
        for (int j = 0; j < 4; ++j) p[j] = f2bfs(v[j] + be[j]);
        *(bf16x4*)(ewe_s + (size_t)rk * 128 + c0) = p;
      }
    }
#pragma unroll
    for (int f = 0; f < 16; ++f) { acc0[f] = (f32x4)0.f; acc1[f] = (f32x4)0.f; }
  }
}

// --------------------------- CSR build --------------------------------------
__global__ void nig_count(const int* __restrict__ dst, int* __restrict__ deg) {
  int e = blockIdx.x * 256 + threadIdx.x;
  if (e < NE) atomicAdd(&deg[dst[e]], 1);
}

__global__ void nig_scan(const int* __restrict__ deg, int* __restrict__ offs,
                         int* __restrict__ cursor) {
  __shared__ int sm[1024];
  const int tid = threadIdx.x;
  int loc[10];
  int s = 0;
#pragma unroll
  for (int i = 0; i < 10; ++i) {
    int idx = tid * 10 + i;
    int d = (idx < NN) ? deg[idx] : 0;
    loc[i] = s; s += d;
  }
  sm[tid] = s;
  __syncthreads();
  for (int d = 1; d < 1024; d <<= 1) {
    int t = (tid >= d) ? sm[tid - d] : 0;
    __syncthreads();
    sm[tid] += t;
    __syncthreads();
  }
  int base = (tid == 0) ? 0 : sm[tid - 1];
#pragma unroll
  for (int i = 0; i < 10; ++i) {
    int idx = tid * 10 + i;
    if (idx < NN) { int v = base + loc[i]; offs[idx] = v; cursor[idx] = v; }
  }
  if (tid == 1023) offs[NN] = base + s;
}

__global__ void nig_scatter(const int* __restrict__ dst, int* __restrict__ cursor,
                            int* __restrict__ rank) {
  int e = blockIdx.x * 256 + threadIdx.x;
  if (e < NE) rank[e] = atomicAdd(&cursor[dst[e]], 1);
}

// ---------------------------------------------------------------------------
// reduce: one wave per dst node; CSR-sorted inputs -> streaming reads.
// 4-wide batched inner loop (independent loads) to break latency chains.
// ---------------------------------------------------------------------------
__global__ void nig_reduce(const int* __restrict__ offs,
                           const float* __restrict__ logits_s,
                           const int* __restrict__ src_s,
                           const short* __restrict__ ewe_s,
                           const short* __restrict__ hsB,
                           const float* __restrict__ hdst, const float* __restrict__ hself,
                           const float* __restrict__ bias, float* __restrict__ out) {
  const int node = (blockIdx.x * blockDim.x + threadIdx.x) >> 6;
  const int ln = threadIdx.x & 63;
  if (node >= NN) return;
  const int b0 = offs[node], b1 = offs[node + 1];
  const int deg = b1 - b0;
  const int c2 = ln * 2;

  float mx = -1e30f;
  for (int i = ln; i < deg; i += 64) mx = fmaxf(mx, logits_s[b0 + i]);
#pragma unroll
  for (int o = 32; o > 0; o >>= 1) mx = fmaxf(mx, __shfl_xor(mx, o, 64));

  float den = 0.f, a0 = 0.f, a1 = 0.f;
  int i = 0;
  for (; i + 4 <= deg; i += 4) {
    float lg0 = logits_s[b0 + i],     lg1 = logits_s[b0 + i + 1];
    float lg2 = logits_s[b0 + i + 2], lg3 = logits_s[b0 + i + 3];
    int sn0 = src_s[b0 + i],     sn1 = src_s[b0 + i + 1];
    int sn2 = src_s[b0 + i + 2], sn3 = src_s[b0 + i + 3];
    uint32_t e0 = *(const uint32_t*)(ewe_s + (size_t)(b0 + i) * 128 + c2);
    uint32_t e1 = *(const uint32_t*)(ewe_s + (size_t)(b0 + i + 1) * 128 + c2);
    uint32_t e2 = *(const uint32_t*)(ewe_s + (size_t)(b0 + i + 2) * 128 + c2);
    uint32_t e3 = *(const uint32_t*)(ewe_s + (size_t)(b0 + i + 3) * 128 + c2);
    uint32_t h0 = *(const uint32_t*)(hsB + (size_t)sn0 * 128 + c2);
    uint32_t h1 = *(const uint32_t*)(hsB + (size_t)sn1 * 128 + c2);
    uint32_t h2 = *(const uint32_t*)(hsB + (size_t)sn2 * 128 + c2);
    uint32_t h3 = *(const uint32_t*)(hsB + (size_t)sn3 * 128 + c2);
    float p0 = __expf(lg0 - mx), p1 = __expf(lg1 - mx);
    float p2 = __expf(lg2 - mx), p3 = __expf(lg3 - mx);
    den += (p0 + p1) + (p2 + p3);
    a0 += p0 * bf2f(e0 & 0xffffu) * bf2f(h0 & 0xffffu)
        + p1 * bf2f(e1 & 0xffffu) * bf2f(h1 & 0xffffu)
        + p2 * bf2f(e2 & 0xffffu) * bf2f(h2 & 0xffffu)
        + p3 * bf2f(e3 & 0xffffu) * bf2f(h3 & 0xffffu);
    a1 += p0 * bf2f(e0 >> 16) * bf2f(h0 >> 16)
        + p1 * bf2f(e1 >> 16) * bf2f(h1 >> 16)
        + p2 * bf2f(e2 >> 16) * bf2f(h2 >> 16)
        + p3 * bf2f(e3 >> 16) * bf2f(h3 >> 16);
  }
  for (; i < deg; ++i) {
    float p = __expf(logits_s[b0 + i] - mx);
    uint32_t ee = *(const uint32_t*)(ewe_s + (size_t)(b0 + i) * 128 + c2);
    int sn = src_s[b0 + i];
    uint32_t hh = *(const uint32_t*)(hsB + (size_t)sn * 128 + c2);
    a0 += p * bf2f(ee & 0xffffu) * bf2f(hh & 0xffffu);
    a1 += p * bf2f(ee >> 16) * bf2f(hh >> 16);
    den += p;
  }
  float inv = (deg > 0) ? 1.0f / den : 0.f;
  f32x2 hd = *(const f32x2*)(hdst + (size_t)node * 128 + c2);
  f32x2 hs = *(const f32x2*)(hself + (size_t)node * 128 + c2);
  f32x2 bb = *(const f32x2*)(bias + c2);
  f32x2 o;
  o[0] = hs[0] + bb[0] + hd[0] * a0 * inv;
  o[1] = hs[1] + bb[1] + hd[1] * a1 * inv;
  *(f32x2*)(out + (size_t)node * 128 + c2) = o;
}

// ---------------------------------------------------------------------------
extern "C" void kernel_launch(void* const* d_in, const int* in_sizes, int n_in,
                              void* d_out, int out_size, void* d_ws, size_t ws_size,
                              hipStream_t stream) {
  const float* feat      = (const float*)d_in[0];
  const float* edge_w    = (const float*)d_in[1];
  const float* W_neigh   = (const float*)d_in[2];
  const float* W_dstM    = (const float*)d_in[3];
  const float* W_self    = (const float*)d_in[4];
  const float* W_edge    = (const float*)d_in[5];
  const float* b_edge    = (const float*)d_in[6];
  const float* W_prj_src = (const float*)d_in[7];
  const float* b_prj_src = (const float*)d_in[8];
  const float* W_prj_dst = (const float*)d_in[9];
  const float* b_prj_dst = (const float*)d_in[10];
  const float* W_prj_edge= (const float*)d_in[11];
  const float* b_prj_edge= (const float*)d_in[12];
  const float* alpha     = (const float*)d_in[13];
  const float* W_att     = (const float*)d_in[14];
  const float* b_att     = (const float*)d_in[15];
  const float* bias      = (const float*)d_in[16];
  const int*   src       = (const int*)d_in[17];
  const int*   dst       = (const int*)d_in[18];
  float* out = (float*)d_out;

  char* ws = (char*)d_ws;
  size_t off = 0;
  auto alloc = [&](size_t bytes) -> void* {
    void* p = ws + off;
    off = (off + bytes + 511) & ~(size_t)511;
    return p;
  };
  short* img_edge = (short*)alloc((size_t)8 * 256 * 64);       // 128 KB
  short* img_node = (short*)alloc((size_t)5 * 8 * 128 * 64);   // 320 KB
  float* bsum     = (float*)alloc(128 * 4);
  short* hwS      = (short*)alloc((size_t)NN * 128 * 2);
  short* hwD      = (short*)alloc((size_t)NN * 128 * 2);
  short* hsB      = (short*)alloc((size_t)NN * 128 * 2);
  float* hdst     = (float*)alloc((size_t)NN * 128 * 4);
  float* hself    = (float*)alloc((size_t)NN * 128 * 4);
  float* logits_s = (float*)alloc((size_t)NE * 4);
  int*   src_s    = (int*)alloc((size_t)NE * 4);
  short* ewe_s    = (short*)alloc((size_t)NE * 128 * 2);       // 82 MB
  int*   deg      = (int*)alloc((size_t)NN * 4);
  int*   offsb    = (int*)alloc((size_t)(NN + 1) * 4);
  int*   cursor   = (int*)alloc((size_t)NN * 4);
  int*   rank     = (int*)alloc((size_t)NE * 4);

  hipMemsetAsync(deg, 0, (size_t)NN * 4, stream);

  nig_count<<<dim3((NE + 255) / 256), 256, 0, stream>>>(dst, deg);
  nig_scan<<<dim3(1), 1024, 0, stream>>>(deg, offsb, cursor);
  nig_scatter<<<dim3((NE + 255) / 256), 256, 0, stream>>>(dst, cursor, rank);

  nig_prep<<<dim3(112), 256, 0, stream>>>(
      W_prj_edge, W_edge, W_prj_src, W_prj_dst, W_neigh, W_dstM, W_self,
      b_prj_src, b_prj_dst, b_prj_edge, img_edge, img_node, bsum);

  nig_gemm_node<<<dim3(157, 5), 256, 0, stream>>>(feat, NN, img_node,
                                                  hwS, hwD, hsB, hdst, hself);

  nig_gemm_edge<<<dim3(250), 512, 0, stream>>>(
      edge_w, img_edge, hwS, hwD, bsum, W_att, b_att, alpha, b_edge,
      src, dst, rank, logits_s, src_s, ewe_s);

  nig_reduce<<<dim3((NN + 3) / 4), 256, 0, stream>>>(offsb, logits_s, src_s, ewe_s,
                                                     hsB, hdst, hself, bias, out);
}